// Round 2
// baseline (490.450 us; speedup 1.0000x reference)
//
#include <hip/hip_runtime.h>

// HVAE loss, fused. Output = scalar f32.
// accs layout in d_ws: [0]=softplus sum, [1]=edge gather sum, [2]=KL sum; flag after accs[8].

static constexpr double D_LOG2PI = 1.8378770664093453;   // ln(2*pi)
static constexpr float  KL_C0    = -1.1931471805599453f; // -0.5 + 0.5*ln(0.25)

__device__ __forceinline__ void block_reduce_add(double v, double* acc) {
#pragma unroll
  for (int off = 32; off > 0; off >>= 1)
    v += __shfl_down(v, off, 64);
  __shared__ double s[8];
  const int lane = threadIdx.x & 63;
  const int wv   = threadIdx.x >> 6;
  if (lane == 0) s[wv] = v;
  __syncthreads();
  if (threadIdx.x == 0) {
    double t = s[0];
    const int nw = (blockDim.x + 63) >> 6;
    for (int w = 1; w < nw; ++w) t += s[w];
    atomicAdd(acc, t);
  }
}

// Zero accumulators + detect edge_index storage width (int64 vs int32).
// int64 little-endian with values in [0, 2^31): every odd 32-bit word is 0.
__global__ __launch_bounds__(64) void k_init(double* __restrict__ accs,
                                             int* __restrict__ flag,
                                             const int* __restrict__ eidx) {
  const int t = threadIdx.x;
  if (t < 8) accs[t] = 0.0;
  const int w = eidx[2 * t + 1];
  const unsigned long long m = __ballot(w == 0);
  if (t == 0) *flag = (m == 0xFFFFFFFFFFFFFFFFull) ? 1 : 0;
}

// sum over all N^2 elements of softplus(x) = max(x,0) + log1p(exp(-|x|))
__global__ __launch_bounds__(256) void k_softplus(const float4* __restrict__ x,
                                                  long long n4,
                                                  double* __restrict__ acc) {
  long long i = (long long)blockIdx.x * blockDim.x + threadIdx.x;
  const long long stride = (long long)gridDim.x * blockDim.x;
  double local = 0.0;
  for (; i < n4; i += stride) {
    const float4 v = x[i];
    float s = fmaxf(v.x, 0.f) + log1pf(__expf(-fabsf(v.x)));
    s += fmaxf(v.y, 0.f) + log1pf(__expf(-fabsf(v.y)));
    s += fmaxf(v.z, 0.f) + log1pf(__expf(-fabsf(v.z)));
    s += fmaxf(v.w, 0.f) + log1pf(__expf(-fabsf(v.w)));
    local += (double)s;
  }
  block_reduce_add(local, acc);
}

// sum over edges of x[i,j] + (i!=j ? x[j,i] : 0)   (approximates set-scatter; dup error ~1e-6)
__global__ __launch_bounds__(256) void k_edges(const int* __restrict__ eidx,
                                               const float* __restrict__ x,
                                               int N, int E,
                                               const int* __restrict__ flag,
                                               double* __restrict__ acc) {
  const int is64 = *flag;
  const long long t0 = (long long)blockIdx.x * blockDim.x + threadIdx.x;
  const long long stride = (long long)gridDim.x * blockDim.x;
  double local = 0.0;
  for (long long e = t0; e < E; e += stride) {
    int i, j;
    if (is64) {
      i = eidx[2 * e];
      j = eidx[2 * ((long long)E + e)];
    } else {
      i = eidx[e];
      j = eidx[(long long)E + e];
    }
    float v = x[(long long)i * N + j];
    if (i != j) v += x[(long long)j * N + i];
    local += (double)v;
  }
  block_reduce_add(local, acc);
}

// sum over (N,D) of kl_structure + kl_semantic integrands:
//   f(mu,lv,q) = (-0.5 + 0.5*ln(0.25)) - 0.5*lv + 2*((mu-q)^2 + exp(lv))
// kl_structure: (z_mu_e, z_logvar_e) vs mu_Alpha;  kl_semantic: (z_mu_n, z_logvar_n) vs mu_Beta
__global__ __launch_bounds__(256) void k_kl(const float4* __restrict__ zmu_n,
                                            const float4* __restrict__ zlv_n,
                                            const float4* __restrict__ zmu_e,
                                            const float4* __restrict__ zlv_e,
                                            const float4* __restrict__ muA,
                                            const float4* __restrict__ muB,
                                            long long n4, int d4mask,
                                            double* __restrict__ acc) {
  long long i = (long long)blockIdx.x * blockDim.x + threadIdx.x;
  const long long stride = (long long)gridDim.x * blockDim.x;
  double local = 0.0;
  for (; i < n4; i += stride) {
    const int dv = (int)(i & d4mask);
    const float4 qa = muA[dv];
    const float4 qb = muB[dv];
    const float4 me = zmu_e[i];
    const float4 le = zlv_e[i];
    const float4 mn = zmu_n[i];
    const float4 ln_ = zlv_n[i];
    float s = 0.f;
    {
      float d0 = me.x - qa.x, d1 = me.y - qa.y, d2 = me.z - qa.z, d3 = me.w - qa.w;
      s += KL_C0 - 0.5f * le.x + 2.f * (d0 * d0 + __expf(le.x));
      s += KL_C0 - 0.5f * le.y + 2.f * (d1 * d1 + __expf(le.y));
      s += KL_C0 - 0.5f * le.z + 2.f * (d2 * d2 + __expf(le.z));
      s += KL_C0 - 0.5f * le.w + 2.f * (d3 * d3 + __expf(le.w));
    }
    {
      float d0 = mn.x - qb.x, d1 = mn.y - qb.y, d2 = mn.z - qb.z, d3 = mn.w - qb.w;
      s += KL_C0 - 0.5f * ln_.x + 2.f * (d0 * d0 + __expf(ln_.x));
      s += KL_C0 - 0.5f * ln_.y + 2.f * (d1 * d1 + __expf(ln_.y));
      s += KL_C0 - 0.5f * ln_.z + 2.f * (d2 * d2 + __expf(ln_.z));
      s += KL_C0 - 0.5f * ln_.w + 2.f * (d3 * d3 + __expf(ln_.w));
    }
    local += (double)s;
  }
  block_reduce_add(local, acc);
}

// Small D=64 terms + final combine. One wave.
__global__ __launch_bounds__(64) void k_final(const float* __restrict__ Alpha_mu,
                                              const float* __restrict__ Beta_mu,
                                              const float* __restrict__ mu_A,
                                              const float* __restrict__ mu_B,
                                              const double* __restrict__ accs,
                                              float* __restrict__ out,
                                              int D, double invN2, double invND) {
  const int d = threadIdx.x;
  double t = 0.0;
  if (d < D) {
    const double ma = mu_A[d], mb = mu_B[d];
    const double aa = Alpha_mu[d], bb = Beta_mu[d];
    t = -0.5 * (D_LOG2PI + ma * ma) + 2.0 * (ma - aa) * (ma - aa)
      + -0.5 * (D_LOG2PI + mb * mb) + 2.0 * (mb - bb) * (mb - bb);
  }
#pragma unroll
  for (int off = 32; off > 0; off >>= 1)
    t += __shfl_down(t, off, 64);
  if (d == 0) {
    const double r = (accs[0] - accs[1]) * invN2
                   + accs[2] * invND
                   + t / (double)D;
    out[0] = (float)r;
  }
}

extern "C" void kernel_launch(void* const* d_in, const int* in_sizes, int n_in,
                              void* d_out, int out_size, void* d_ws, size_t ws_size,
                              hipStream_t stream) {
  const float* z_mu_n   = (const float*)d_in[0];
  const float* z_lv_n   = (const float*)d_in[1];
  const float* z_mu_e   = (const float*)d_in[2];
  const float* z_lv_e   = (const float*)d_in[3];
  const float* Alpha_mu = (const float*)d_in[4];
  const float* Beta_mu  = (const float*)d_in[5];
  const float* elog     = (const float*)d_in[6];
  const float* mu_A     = (const float*)d_in[7];
  const float* mu_B     = (const float*)d_in[8];
  const int*   eidx     = (const int*)d_in[9];

  const int D = in_sizes[4];
  const int N = in_sizes[0] / D;
  const int E = in_sizes[9] / 2;
  const long long N2 = (long long)N * N;
  const long long ND = (long long)N * D;

  double* accs = (double*)d_ws;
  int* flag = (int*)(accs + 8);
  float* out = (float*)d_out;

  k_init<<<1, 64, 0, stream>>>(accs, flag, eidx);
  k_softplus<<<4096, 256, 0, stream>>>((const float4*)elog, N2 / 4, accs + 0);
  k_edges<<<1024, 256, 0, stream>>>(eidx, elog, N, E, flag, accs + 1);
  // NOTE: kl_structure/kl_semantic priors are mu_Alpha (d_in[7]) / mu_Beta (d_in[8]),
  // NOT Alpha_mu/Beta_mu (d_in[4]/[5]) — R0 bug.
  k_kl<<<512, 256, 0, stream>>>((const float4*)z_mu_n, (const float4*)z_lv_n,
                                (const float4*)z_mu_e, (const float4*)z_lv_e,
                                (const float4*)mu_A, (const float4*)mu_B,
                                ND / 4, D / 4 - 1, accs + 2);
  k_final<<<1, 64, 0, stream>>>(Alpha_mu, Beta_mu, mu_A, mu_B, accs, out,
                                D, 1.0 / (double)N2, 1.0 / (double)ND);
}

// Round 4
// 404.421 us; speedup vs baseline: 1.2127x; 1.2127x over previous
//
#include <hip/hip_runtime.h>

// HVAE loss, fused. Output = scalar f32.
// accs layout in d_ws: [0]=softplus sum, [1]=edge gather sum, [2]=KL sum; flag after accs[8].

static constexpr double D_LOG2PI = 1.8378770664093453;   // ln(2*pi)
static constexpr float  KL_C0    = -1.1931471805599453f; // -0.5 + 0.5*ln(0.25)

__device__ __forceinline__ void block_reduce_add(double v, double* acc) {
#pragma unroll
  for (int off = 32; off > 0; off >>= 1)
    v += __shfl_down(v, off, 64);
  __shared__ double s[8];
  const int lane = threadIdx.x & 63;
  const int wv   = threadIdx.x >> 6;
  if (lane == 0) s[wv] = v;
  __syncthreads();
  if (threadIdx.x == 0) {
    double t = s[0];
    const int nw = (blockDim.x + 63) >> 6;
    for (int w = 1; w < nw; ++w) t += s[w];
    atomicAdd(acc, t);
  }
}

// softplus(x) = max(x,0) + ln2 * log2(1 + 2^(-|x|*log2e))
// 2 HW transcendentals (v_exp_f32 / v_log_f32 are base-2 native on gfx950)
// instead of libm log1pf+expf. abs err <~1e-7 — negligible vs 0.357 threshold.
__device__ __forceinline__ float softplus_fast(float x) {
  const float t = __builtin_amdgcn_exp2f(-1.442695041f * fabsf(x));
  return fmaxf(x, 0.f) + 0.6931471806f * __builtin_amdgcn_logf(1.f + t);
}

// Zero accumulators + detect edge_index storage width (int64 vs int32).
// int64 little-endian with values in [0, 2^31): every odd 32-bit word is 0.
__global__ __launch_bounds__(64) void k_init(double* __restrict__ accs,
                                             int* __restrict__ flag,
                                             const int* __restrict__ eidx) {
  const int t = threadIdx.x;
  if (t < 8) accs[t] = 0.0;
  const int w = eidx[2 * t + 1];
  const unsigned long long m = __ballot(w == 0);
  if (t == 0) *flag = (m == 0xFFFFFFFFFFFFFFFFull) ? 1 : 0;
}

// One fused kernel, block-range partitioned (wave-uniform branch):
//   blocks [0, spB)                : softplus sum over N^2 logits
//   blocks [spB, spB+edB)          : per-edge symmetric gather sum
//   blocks [spB+edB, spB+edB+klB)  : KL sum over (N,D) latents
// Fusing lets the latency-bound edge gathers overlap the BW-bound scan.
__global__ __launch_bounds__(256) void k_main(
    const float4* __restrict__ x4, long long n4,
    const int* __restrict__ eidx, const float* __restrict__ x, int N, int E,
    const int* __restrict__ flag,
    const float4* __restrict__ zmu_n, const float4* __restrict__ zlv_n,
    const float4* __restrict__ zmu_e, const float4* __restrict__ zlv_e,
    const float4* __restrict__ muA, const float4* __restrict__ muB,
    long long nd4, int d4mask,
    double* __restrict__ accs, int spB, int edB) {
  const int b = blockIdx.x;
  if (b < spB) {
    // ---- softplus scan ----
    long long i = (long long)b * blockDim.x + threadIdx.x;
    const long long stride = (long long)spB * blockDim.x;
    double local = 0.0;
    for (; i < n4; i += stride) {
      const float4 v = x4[i];
      float s = softplus_fast(v.x) + softplus_fast(v.y)
              + softplus_fast(v.z) + softplus_fast(v.w);
      local += (double)s;
    }
    block_reduce_add(local, accs + 0);
  } else if (b < spB + edB) {
    // ---- edge gather: x[i,j] + (i!=j ? x[j,i] : 0) ----
    const int is64 = *flag;
    const long long t0 = (long long)(b - spB) * blockDim.x + threadIdx.x;
    const long long stride = (long long)edB * blockDim.x;
    double local = 0.0;
    for (long long e = t0; e < E; e += stride) {
      int i, j;
      if (is64) {
        i = eidx[2 * e];
        j = eidx[2 * ((long long)E + e)];
      } else {
        i = eidx[e];
        j = eidx[(long long)E + e];
      }
      float v = x[(long long)i * N + j];
      if (i != j) v += x[(long long)j * N + i];
      local += (double)v;
    }
    block_reduce_add(local, accs + 1);
  } else {
    // ---- KL over latents: f(mu,lv,q) = KL_C0 - 0.5*lv + 2*((mu-q)^2 + exp(lv)) ----
    long long i = (long long)(b - spB - edB) * blockDim.x + threadIdx.x;
    const long long stride = (long long)(gridDim.x - spB - edB) * blockDim.x;
    double local = 0.0;
    for (; i < nd4; i += stride) {
      const int dv = (int)(i & d4mask);
      const float4 qa = muA[dv];
      const float4 qb = muB[dv];
      const float4 me = zmu_e[i];
      const float4 le = zlv_e[i];
      const float4 mn = zmu_n[i];
      const float4 ln_ = zlv_n[i];
      float s = 0.f;
      {
        float d0 = me.x - qa.x, d1 = me.y - qa.y, d2 = me.z - qa.z, d3 = me.w - qa.w;
        s += KL_C0 - 0.5f * le.x + 2.f * (d0 * d0 + __expf(le.x));
        s += KL_C0 - 0.5f * le.y + 2.f * (d1 * d1 + __expf(le.y));
        s += KL_C0 - 0.5f * le.z + 2.f * (d2 * d2 + __expf(le.z));
        s += KL_C0 - 0.5f * le.w + 2.f * (d3 * d3 + __expf(le.w));
      }
      {
        float d0 = mn.x - qb.x, d1 = mn.y - qb.y, d2 = mn.z - qb.z, d3 = mn.w - qb.w;
        s += KL_C0 - 0.5f * ln_.x + 2.f * (d0 * d0 + __expf(ln_.x));
        s += KL_C0 - 0.5f * ln_.y + 2.f * (d1 * d1 + __expf(ln_.y));
        s += KL_C0 - 0.5f * ln_.z + 2.f * (d2 * d2 + __expf(ln_.z));
        s += KL_C0 - 0.5f * ln_.w + 2.f * (d3 * d3 + __expf(ln_.w));
      }
      local += (double)s;
    }
    block_reduce_add(local, accs + 2);
  }
}

// Small D=64 terms + final combine. One wave.
__global__ __launch_bounds__(64) void k_final(const float* __restrict__ Alpha_mu,
                                              const float* __restrict__ Beta_mu,
                                              const float* __restrict__ mu_A,
                                              const float* __restrict__ mu_B,
                                              const double* __restrict__ accs,
                                              float* __restrict__ out,
                                              int D, double invN2, double invND) {
  const int d = threadIdx.x;
  double t = 0.0;
  if (d < D) {
    const double ma = mu_A[d], mb = mu_B[d];
    const double aa = Alpha_mu[d], bb = Beta_mu[d];
    t = -0.5 * (D_LOG2PI + ma * ma) + 2.0 * (ma - aa) * (ma - aa)
      + -0.5 * (D_LOG2PI + mb * mb) + 2.0 * (mb - bb) * (mb - bb);
  }
#pragma unroll
  for (int off = 32; off > 0; off >>= 1)
    t += __shfl_down(t, off, 64);
  if (d == 0) {
    const double r = (accs[0] - accs[1]) * invN2
                   + accs[2] * invND
                   + t / (double)D;
    out[0] = (float)r;
  }
}

extern "C" void kernel_launch(void* const* d_in, const int* in_sizes, int n_in,
                              void* d_out, int out_size, void* d_ws, size_t ws_size,
                              hipStream_t stream) {
  const float* z_mu_n   = (const float*)d_in[0];
  const float* z_lv_n   = (const float*)d_in[1];
  const float* z_mu_e   = (const float*)d_in[2];
  const float* z_lv_e   = (const float*)d_in[3];
  const float* Alpha_mu = (const float*)d_in[4];
  const float* Beta_mu  = (const float*)d_in[5];
  const float* elog     = (const float*)d_in[6];
  const float* mu_A     = (const float*)d_in[7];
  const float* mu_B     = (const float*)d_in[8];
  const int*   eidx     = (const int*)d_in[9];

  const int D = in_sizes[4];
  const int N = in_sizes[0] / D;
  const int E = in_sizes[9] / 2;
  const long long N2 = (long long)N * N;
  const long long ND = (long long)N * D;

  double* accs = (double*)d_ws;
  int* flag = (int*)(accs + 8);
  float* out = (float*)d_out;

  const int spB = 4096, edB = 1024, klB = 256;

  k_init<<<1, 64, 0, stream>>>(accs, flag, eidx);
  k_main<<<spB + edB + klB, 256, 0, stream>>>(
      (const float4*)elog, N2 / 4,
      eidx, elog, N, E, flag,
      (const float4*)z_mu_n, (const float4*)z_lv_n,
      (const float4*)z_mu_e, (const float4*)z_lv_e,
      (const float4*)mu_A, (const float4*)mu_B,
      ND / 4, D / 4 - 1,
      accs, spB, edB);
  k_final<<<1, 64, 0, stream>>>(Alpha_mu, Beta_mu, mu_A, mu_B, accs, out,
                                D, 1.0 / (double)N2, 1.0 / (double)ND);
}

// Round 5
// 394.890 us; speedup vs baseline: 1.2420x; 1.0241x over previous
//
#include <hip/hip_runtime.h>

// HVAE loss, fused. Output = scalar f32.
// ws layout: one double partial per block of k_main (no zeroing needed — every
// slot is written before k_final reads it, so the 0xAA poison is harmless).

static constexpr double D_LOG2PI = 1.8378770664093453;   // ln(2*pi)
static constexpr float  KL_C0    = -1.1931471805599453f; // -0.5 + 0.5*ln(0.25)

// softplus(x) = max(x,0) + ln2 * log2(1 + 2^(-|x|*log2e))
// v_exp_f32 / v_log_f32 are base-2 native on gfx950; abs err <~1e-7.
__device__ __forceinline__ float softplus_fast(float x) {
  const float t = __builtin_amdgcn_exp2f(-1.442695041f * fabsf(x));
  return fmaxf(x, 0.f) + 0.6931471806f * __builtin_amdgcn_logf(1.f + t);
}

__device__ __forceinline__ float sp4(const float4 v) {
  return softplus_fast(v.x) + softplus_fast(v.y)
       + softplus_fast(v.z) + softplus_fast(v.w);
}

// Reduce across the block, store ONE double to this block's unique slot.
__device__ __forceinline__ void block_reduce_store(double v, double* slot) {
#pragma unroll
  for (int off = 32; off > 0; off >>= 1)
    v += __shfl_down(v, off, 64);
  __shared__ double s[4];
  const int lane = threadIdx.x & 63;
  const int wv   = threadIdx.x >> 6;
  if (lane == 0) s[wv] = v;
  __syncthreads();
  if (threadIdx.x == 0) *slot = s[0] + s[1] + s[2] + s[3];
}

// One fused kernel, block-range partitioned (wave-uniform branch):
//   blocks [0, spB)            : softplus sum over N^2 logits (4x-unrolled MLP)
//   blocks [spB, spB+edB)      : per-edge symmetric gather sum
//   blocks [spB+edB, grid)     : KL sum over (N,D) latents
__global__ __launch_bounds__(256) void k_main(
    const float4* __restrict__ x4, long long n4,
    const int* __restrict__ eidx, const float* __restrict__ x, int N, int E,
    const float4* __restrict__ zmu_n, const float4* __restrict__ zlv_n,
    const float4* __restrict__ zmu_e, const float4* __restrict__ zlv_e,
    const float4* __restrict__ muA, const float4* __restrict__ muB,
    long long nd4, int d4mask,
    double* __restrict__ partials, int spB, int edB) {
  const int b = blockIdx.x;
  if (b < spB) {
    // ---- softplus scan, 4 independent loads in flight ----
    const long long S = (long long)spB * blockDim.x;
    long long i = (long long)b * blockDim.x + threadIdx.x;
    double local = 0.0;
    for (; i + 3 * S < n4; i += 4 * S) {
      const float4 a = x4[i];
      const float4 c = x4[i + S];
      const float4 d = x4[i + 2 * S];
      const float4 e = x4[i + 3 * S];
      local += (double)(sp4(a) + sp4(c) + sp4(d) + sp4(e));
    }
    for (; i < n4; i += S) local += (double)sp4(x4[i]);
    block_reduce_store(local, partials + b);
  } else if (b < spB + edB) {
    // ---- edge gather: x[i,j] + (i!=j ? x[j,i] : 0) ----
    // Per-wave int64-vs-int32 layout detection: int64 little-endian with
    // values < 2^31 has every odd 32-bit word == 0.
    const int w0 = eidx[2 * (threadIdx.x & 63) + 1];
    const int is64 = (__ballot(w0 == 0) == 0xFFFFFFFFFFFFFFFFull) ? 1 : 0;
    const long long t0 = (long long)(b - spB) * blockDim.x + threadIdx.x;
    const long long stride = (long long)edB * blockDim.x;
    double local = 0.0;
    for (long long e = t0; e < E; e += stride) {
      int i, j;
      if (is64) {
        i = eidx[2 * e];
        j = eidx[2 * ((long long)E + e)];
      } else {
        i = eidx[e];
        j = eidx[(long long)E + e];
      }
      float v = x[(long long)i * N + j];
      if (i != j) v += x[(long long)j * N + i];
      local += (double)v;
    }
    block_reduce_store(local, partials + b);
  } else {
    // ---- KL over latents: f(mu,lv,q) = KL_C0 - 0.5*lv + 2*((mu-q)^2 + exp(lv)) ----
    long long i = (long long)(b - spB - edB) * blockDim.x + threadIdx.x;
    const long long stride = (long long)(gridDim.x - spB - edB) * blockDim.x;
    double local = 0.0;
    for (; i < nd4; i += stride) {
      const int dv = (int)(i & d4mask);
      const float4 qa = muA[dv];
      const float4 qb = muB[dv];
      const float4 me = zmu_e[i];
      const float4 le = zlv_e[i];
      const float4 mn = zmu_n[i];
      const float4 ln_ = zlv_n[i];
      float s = 0.f;
      {
        float d0 = me.x - qa.x, d1 = me.y - qa.y, d2 = me.z - qa.z, d3 = me.w - qa.w;
        s += KL_C0 - 0.5f * le.x + 2.f * (d0 * d0 + __expf(le.x));
        s += KL_C0 - 0.5f * le.y + 2.f * (d1 * d1 + __expf(le.y));
        s += KL_C0 - 0.5f * le.z + 2.f * (d2 * d2 + __expf(le.z));
        s += KL_C0 - 0.5f * le.w + 2.f * (d3 * d3 + __expf(le.w));
      }
      {
        float d0 = mn.x - qb.x, d1 = mn.y - qb.y, d2 = mn.z - qb.z, d3 = mn.w - qb.w;
        s += KL_C0 - 0.5f * ln_.x + 2.f * (d0 * d0 + __expf(ln_.x));
        s += KL_C0 - 0.5f * ln_.y + 2.f * (d1 * d1 + __expf(ln_.y));
        s += KL_C0 - 0.5f * ln_.z + 2.f * (d2 * d2 + __expf(ln_.z));
        s += KL_C0 - 0.5f * ln_.w + 2.f * (d3 * d3 + __expf(ln_.w));
      }
      local += (double)s;
    }
    block_reduce_store(local, partials + b);
  }
}

// Weighted reduction of all block partials + tiny D=64 scalar terms.
__global__ __launch_bounds__(1024) void k_final(
    const double* __restrict__ partials, int nB, int spB, int edB,
    const float* __restrict__ Alpha_mu, const float* __restrict__ Beta_mu,
    const float* __restrict__ mu_A, const float* __restrict__ mu_B,
    float* __restrict__ out, int D, double invN2, double invND) {
  const int tid = threadIdx.x;
  double local = 0.0;
  for (int b = tid; b < nB; b += 1024) {
    const double w = (b < spB) ? invN2 : ((b < spB + edB) ? -invN2 : invND);
    local += partials[b] * w;
  }
  if (tid < D) {
    const double ma = mu_A[tid], mb = mu_B[tid];
    const double aa = Alpha_mu[tid], bb = Beta_mu[tid];
    const double t = -0.5 * (D_LOG2PI + ma * ma) + 2.0 * (ma - aa) * (ma - aa)
                   + -0.5 * (D_LOG2PI + mb * mb) + 2.0 * (mb - bb) * (mb - bb);
    local += t / (double)D;
  }
#pragma unroll
  for (int off = 32; off > 0; off >>= 1)
    local += __shfl_down(local, off, 64);
  __shared__ double s[16];
  const int lane = tid & 63;
  const int wv   = tid >> 6;
  if (lane == 0) s[wv] = local;
  __syncthreads();
  if (tid == 0) {
    double t = 0.0;
#pragma unroll
    for (int w = 0; w < 16; ++w) t += s[w];
    out[0] = (float)t;
  }
}

extern "C" void kernel_launch(void* const* d_in, const int* in_sizes, int n_in,
                              void* d_out, int out_size, void* d_ws, size_t ws_size,
                              hipStream_t stream) {
  const float* z_mu_n   = (const float*)d_in[0];
  const float* z_lv_n   = (const float*)d_in[1];
  const float* z_mu_e   = (const float*)d_in[2];
  const float* z_lv_e   = (const float*)d_in[3];
  const float* Alpha_mu = (const float*)d_in[4];
  const float* Beta_mu  = (const float*)d_in[5];
  const float* elog     = (const float*)d_in[6];
  const float* mu_A     = (const float*)d_in[7];
  const float* mu_B     = (const float*)d_in[8];
  const int*   eidx     = (const int*)d_in[9];

  const int D = in_sizes[4];
  const int N = in_sizes[0] / D;
  const int E = in_sizes[9] / 2;
  const long long N2 = (long long)N * N;
  const long long ND = (long long)N * D;

  double* partials = (double*)d_ws;
  float* out = (float*)d_out;

  const int spB = 4096, edB = 512, klB = 128;
  const int nB = spB + edB + klB;

  k_main<<<nB, 256, 0, stream>>>(
      (const float4*)elog, N2 / 4,
      eidx, elog, N, E,
      (const float4*)z_mu_n, (const float4*)z_lv_n,
      (const float4*)z_mu_e, (const float4*)z_lv_e,
      (const float4*)mu_A, (const float4*)mu_B,
      ND / 4, D / 4 - 1,
      partials, spB, edB);
  k_final<<<1, 1024, 0, stream>>>(partials, nB, spB, edB,
                                  Alpha_mu, Beta_mu, mu_A, mu_B, out,
                                  D, 1.0 / (double)N2, 1.0 / (double)ND);
}